// Round 14
// baseline (149.489 us; speedup 1.0000x reference)
//
#include <hip/hip_runtime.h>
#include <hip/hip_bf16.h>

typedef __attribute__((ext_vector_type(8))) short bf16x8;
typedef __attribute__((ext_vector_type(4))) float f32x4;

#define NGRAPH   4096
#define NNODES   262144
#define LATENT   256
#define H2       512
#define HID      256
#define NF       128

#define WTOT     (2 * LATENT * H2 + HID * NF)   // 294912

#define TR_BLOCKS 64           // weight transpose: blocks 0..63
#define SC_BLOCKS 64           // seg scan:         blocks 64..127
#define IPT       8            // ints per scan thread (64*512*8 = 262144)

#define GPB      16            // graphs per block (mlp role)
#define THREADS  512           // 8 waves
#define MLP_BLOCKS (NGRAPH / GPB)          // 256; total grid = 128 + 256
#define TOTAL_BLOCKS (TR_BLOCKS + SC_BLOCKS + MLP_BLOCKS)   // 384

// padded LDS strides
#define ZS_S 264
#define HS_S 520
#define HD_S 264

static __device__ __forceinline__ short f2bf(float x) {
    union { float f; unsigned u; } c; c.f = x;
    unsigned r = c.u + 0x7fffu + ((c.u >> 16) & 1u);   // RTNE
    return (short)(r >> 16);
}

// ---------------------------------------------------------------------------
// single dispatch: producer blocks (transpose, scan) + consumer blocks
// (16-graph MLP + streaming scatter), synchronized by device-scope flags.
// Co-residency guaranteed by capacity: LDS 41984 B -> 3 blocks/CU, 768 >= 384.
// ---------------------------------------------------------------------------
__global__ __launch_bounds__(THREADS) void fused_kernel(
    const float* __restrict__ z, const int* __restrict__ seg,
    const float* __restrict__ wlp, const float* __restrict__ w1,
    const float* __restrict__ w2,
    const float* __restrict__ b_lp, const float* __restrict__ b1,
    const float* __restrict__ b2,
    short* __restrict__ wlp_t, short* __restrict__ w1_t,
    short* __restrict__ w2_t, int* __restrict__ offs,
    int* __restrict__ wflag, int* __restrict__ sflag,
    float* __restrict__ out)
{
    __shared__ short zs[GPB * ZS_S];
    __shared__ short hs[GPB * HS_S];
    __shared__ short hd[GPB * HD_S];
    __shared__ float ous[GPB * NF];
    __shared__ int   offl[GPB + 1];

    const int tid = threadIdx.x;
    const int b   = blockIdx.x;

    // ================= producer role 1: weight transpose ====================
    if (b < TR_BLOCKS) {
        const int t = b * THREADS + tid;             // 0..32767
        #pragma unroll
        for (int j = 0; j < WTOT / (TR_BLOCKS * THREADS); ++j) {   // 9
            int i = t + j * (TR_BLOCKS * THREADS);
            if (i < LATENT * H2) {                       // wlp_t [512][256]
                int n = i >> 8, k = i & 255;
                wlp_t[i] = f2bf(wlp[k * H2 + n]);
            } else if (i < 2 * LATENT * H2) {            // w1_t [256][512]
                int jj = i - LATENT * H2;
                int n = jj >> 9, k = jj & 511;
                w1_t[jj] = f2bf(w1[k * HID + n]);
            } else {                                     // w2_t [128][256]
                int jj = i - 2 * LATENT * H2;
                int n = jj >> 8, k = jj & 255;
                w2_t[jj] = f2bf(w2[k * NF + n]);
            }
        }
        __threadfence();
        __syncthreads();
        if (tid == 0)
            __hip_atomic_fetch_add(wflag, 1, __ATOMIC_RELEASE, __HIP_MEMORY_SCOPE_AGENT);
        return;
    }

    // ================= producer role 2: seg scan -> offs ====================
    if (b < TR_BLOCKS + SC_BLOCKS) {
        const int st = (b - TR_BLOCKS) * THREADS + tid;  // 0..32767
        const int base = st * IPT;
        int prev = (base == 0) ? -1 : seg[base - 1];
        int cur[IPT];
        #pragma unroll
        for (int j = 0; j < IPT; ++j) cur[j] = seg[base + j];
        #pragma unroll
        for (int j = 0; j < IPT; ++j) {
            int i = base + j;
            int s = cur[j];
            if (s != prev) {
                for (int g = prev + 1; g <= s; ++g) offs[g] = i;
            }
            prev = s;
        }
        if (base + IPT == NNODES) {
            for (int g = prev + 1; g <= NGRAPH; ++g) offs[g] = NNODES;
        }
        __threadfence();
        __syncthreads();
        if (tid == 0)
            __hip_atomic_fetch_add(sflag, 1, __ATOMIC_RELEASE, __HIP_MEMORY_SCOPE_AGENT);
        return;
    }

    // ================= consumer role: MLP + scatter =========================
    const int w   = tid >> 6;          // wave 0..7
    const int l15 = tid & 15;
    const int lq  = (tid >> 4) & 3;
    const int gbase = (b - TR_BLOCKS - SC_BLOCKS) * GPB;

    // ---- stage z first (no dependency on producers)
    {
        const float4* zsrc = (const float4*)(z + (size_t)gbase * LATENT);
        #pragma unroll
        for (int it = 0; it < (GPB * LATENT / 4) / THREADS; ++it) {
            int idx = tid + it * THREADS;
            int row = idx >> 6, c4 = idx & 63;
            float4 v = zsrc[idx];
            short4 s4;
            s4.x = f2bf(v.x); s4.y = f2bf(v.y); s4.z = f2bf(v.z); s4.w = f2bf(v.w);
            *(short4*)&zs[row * ZS_S + c4 * 4] = s4;
        }
    }

    // ---- wait for weights (overlaps transpose)
    if (tid == 0) {
        while (__hip_atomic_load(wflag, __ATOMIC_ACQUIRE, __HIP_MEMORY_SCOPE_AGENT) < TR_BLOCKS) {}
    }
    __syncthreads();

    // ---- h = relu(z @ Wlp + b_lp), [16 x 512], K=256
    {
        const int cb = w * 64;
        f32x4 acc[4];
        #pragma unroll
        for (int ct = 0; ct < 4; ++ct) acc[ct] = (f32x4){0.f, 0.f, 0.f, 0.f};
        #pragma unroll
        for (int ks = 0; ks < LATENT / 32; ++ks) {
            bf16x8 a = *(const bf16x8*)&zs[l15 * ZS_S + ks * 32 + lq * 8];
            #pragma unroll
            for (int ct = 0; ct < 4; ++ct) {
                bf16x8 bb = *(const bf16x8*)&wlp_t[(cb + ct * 16 + l15) * LATENT + ks * 32 + lq * 8];
                acc[ct] = __builtin_amdgcn_mfma_f32_16x16x32_bf16(a, bb, acc[ct], 0, 0, 0);
            }
        }
        #pragma unroll
        for (int ct = 0; ct < 4; ++ct) {
            const int col = cb + ct * 16 + l15;
            const float bias = b_lp[col];
            #pragma unroll
            for (int i = 0; i < 4; ++i) {
                float v = acc[ct][i] + bias;
                hs[(lq * 4 + i) * HS_S + col] = f2bf(fmaxf(v, 0.f));
            }
        }
    }
    __syncthreads();

    // ---- hid = relu(h @ W1 + b1), [16 x 256], K=512
    {
        const int cb = w * 32;
        f32x4 acc[2];
        #pragma unroll
        for (int ct = 0; ct < 2; ++ct) acc[ct] = (f32x4){0.f, 0.f, 0.f, 0.f};
        #pragma unroll
        for (int ks = 0; ks < H2 / 32; ++ks) {
            bf16x8 a = *(const bf16x8*)&hs[l15 * HS_S + ks * 32 + lq * 8];
            #pragma unroll
            for (int ct = 0; ct < 2; ++ct) {
                bf16x8 bb = *(const bf16x8*)&w1_t[(cb + ct * 16 + l15) * H2 + ks * 32 + lq * 8];
                acc[ct] = __builtin_amdgcn_mfma_f32_16x16x32_bf16(a, bb, acc[ct], 0, 0, 0);
            }
        }
        #pragma unroll
        for (int ct = 0; ct < 2; ++ct) {
            const int col = cb + ct * 16 + l15;
            const float bias = b1[col];
            #pragma unroll
            for (int i = 0; i < 4; ++i) {
                float v = acc[ct][i] + bias;
                hd[(lq * 4 + i) * HD_S + col] = f2bf(fmaxf(v, 0.f));
            }
        }
    }
    __syncthreads();

    // ---- out_u = hid @ W2 + b2, [16 x 128], K=256
    {
        const int cb = w * 16;
        f32x4 acc = (f32x4){0.f, 0.f, 0.f, 0.f};
        #pragma unroll
        for (int ks = 0; ks < HID / 32; ++ks) {
            bf16x8 a = *(const bf16x8*)&hd[l15 * HD_S + ks * 32 + lq * 8];
            bf16x8 bb = *(const bf16x8*)&w2_t[(cb + l15) * HID + ks * 32 + lq * 8];
            acc = __builtin_amdgcn_mfma_f32_16x16x32_bf16(a, bb, acc, 0, 0, 0);
        }
        const int col = cb + l15;
        const float bias = b2[col];
        #pragma unroll
        for (int i = 0; i < 4; ++i)
            ous[(lq * 4 + i) * NF + col] = acc[i] + bias;
    }

    // ---- wait for offs (scan finished long ago; near-zero wait)
    if (tid == 0) {
        while (__hip_atomic_load(sflag, __ATOMIC_ACQUIRE, __HIP_MEMORY_SCOPE_AGENT) < SC_BLOCKS) {}
    }
    __syncthreads();
    if (tid < GPB + 1) offl[tid] = offs[gbase + tid];
    __syncthreads();

    // ---- scatter: wave w broadcasts graphs gbase+2w, gbase+2w+1
    {
        const int lane = tid & 63;
        f32x4* out4 = (f32x4*)out;
        #pragma unroll
        for (int q = 0; q < 2; ++q) {
            const int r = w * 2 + q;               // local row 0..15
            const int lo = offl[r];
            const int hi = offl[r + 1];
            const f32x4 v = *(const f32x4*)&ous[r * NF + (lane & 31) * 4];
            for (int i = lo * (NF / 4) + lane; i < hi * (NF / 4); i += 64)
                out4[i] = v;
        }
    }
}

// ---------------------------------------------------------------------------
extern "C" void kernel_launch(void* const* d_in, const int* in_sizes, int n_in,
                              void* d_out, int out_size, void* d_ws, size_t ws_size,
                              hipStream_t stream) {
    const float* z    = (const float*)d_in[0];
    const int*   seg  = (const int*)  d_in[1];
    const float* wlp  = (const float*)d_in[2];
    const float* b_lp = (const float*)d_in[3];
    const float* w1   = (const float*)d_in[4];
    const float* b1   = (const float*)d_in[5];
    const float* w2   = (const float*)d_in[6];
    const float* b2   = (const float*)d_in[7];
    float* out = (float*)d_out;

    short* wlp_t = (short*)d_ws;                 // [512][256] bf16
    short* w1_t  = wlp_t + LATENT * H2;          // [256][512] bf16
    short* w2_t  = w1_t + H2 * HID;              // [128][256] bf16
    int*   offs  = (int*)(w2_t + HID * NF);      // [4097]
    int*   flags = offs + NGRAPH + 1;            // [2]: wflag, sflag

    hipMemsetAsync(flags, 0, 2 * sizeof(int), stream);
    fused_kernel<<<TOTAL_BLOCKS, THREADS, 0, stream>>>(
        z, seg, wlp, w1, w2, b_lp, b1, b2,
        wlp_t, w1_t, w2_t, offs, flags, flags + 1, out);
}

// Round 15
// 49.343 us; speedup vs baseline: 3.0296x; 3.0296x over previous
//
#include <hip/hip_runtime.h>
#include <hip/hip_bf16.h>

typedef __attribute__((ext_vector_type(8))) short bf16x8;
typedef __attribute__((ext_vector_type(4))) float f32x4;

#define NGRAPH   4096
#define NNODES   262144
#define LATENT   256
#define H2       512
#define HID      256
#define NF       128

#define PREP_BLOCKS 1152       // weight transpose (294912 / 256)
#define SCAN_BLOCKS 64         // seg -> offs scan
#define IPT         16         // ints per scan thread (64*256*16 = 262144)

#define GPB      16            // graphs per block (merged kernel)
#define MTHREADS 1024          // 16 waves: 8 compute, 16 store
#define MBLOCKS  (NGRAPH / GPB)            // 256 -> 1 block/CU

// padded LDS strides
#define ZS_S 264
#define HS_S 520
#define HD_S 264

static __device__ __forceinline__ short f2bf(float x) {
    union { float f; unsigned u; } c; c.f = x;
    unsigned r = c.u + 0x7fffu + ((c.u >> 16) & 1u);   // RTNE
    return (short)(r >> 16);
}

// ---------------------------------------------------------------------------
// dispatch 1: weight transpose -> bf16 (blocks 0..1151) + seg scan -> offs
// (blocks 1152..1215).  offs[g] = first node index with seg >= g.
// ---------------------------------------------------------------------------
__global__ __launch_bounds__(256) void prep_kernel(
    const float* __restrict__ wlp, const float* __restrict__ w1,
    const float* __restrict__ w2, const int* __restrict__ seg,
    short* __restrict__ wlp_t, short* __restrict__ w1_t, short* __restrict__ w2_t,
    int* __restrict__ offs)
{
    const int b = blockIdx.x;
    if (b < PREP_BLOCKS) {
        int i = b * 256 + threadIdx.x;
        if (i < LATENT * H2) {                       // wlp_t [512][256]
            int n = i >> 8, k = i & 255;
            wlp_t[i] = f2bf(wlp[k * H2 + n]);
        } else if (i < 2 * LATENT * H2) {            // w1_t [256][512]
            int j = i - LATENT * H2;
            int n = j >> 9, k = j & 511;
            w1_t[j] = f2bf(w1[k * HID + n]);
        } else if (i < 2 * LATENT * H2 + HID * NF) { // w2_t [128][256]
            int j = i - 2 * LATENT * H2;
            int n = j >> 8, k = j & 255;
            w2_t[j] = f2bf(w2[k * NF + n]);
        }
    } else {
        const int st = (b - PREP_BLOCKS) * 256 + threadIdx.x;   // 0..16383
        const int base = st * IPT;
        int prev = (base == 0) ? -1 : seg[base - 1];
        int cur[IPT];
        #pragma unroll
        for (int j = 0; j < IPT; ++j) cur[j] = seg[base + j];
        #pragma unroll
        for (int j = 0; j < IPT; ++j) {
            int i = base + j;
            int s = cur[j];
            if (s != prev) {
                for (int g = prev + 1; g <= s; ++g) offs[g] = i;
            }
            prev = s;
        }
        if (base + IPT == NNODES) {                  // tail: (seg[N-1], NGRAPH]
            for (int g = prev + 1; g <= NGRAPH; ++g) offs[g] = NNODES;
        }
    }
}

// ---------------------------------------------------------------------------
// dispatch 2: 16-graph MLP (waves 0-7) + streaming scatter (all 16 waves,
// 1 graph per wave) via LDS.  256 blocks = 1/CU; 16 waves/CU storing.
// ---------------------------------------------------------------------------
__global__ __launch_bounds__(MTHREADS) void mlp_scatter_kernel(
    const float* __restrict__ z, const int* __restrict__ offs,
    const short* __restrict__ wlp_t, const short* __restrict__ w1_t,
    const short* __restrict__ w2_t,
    const float* __restrict__ b_lp, const float* __restrict__ b1,
    const float* __restrict__ b2,
    float* __restrict__ out)
{
    __shared__ short zs[GPB * ZS_S];
    __shared__ short hs[GPB * HS_S];
    __shared__ short hd[GPB * HD_S];
    __shared__ float ous[GPB * NF];
    __shared__ int   offl[GPB + 1];

    const int tid = threadIdx.x;
    const int w   = tid >> 6;          // wave 0..15
    const int l15 = tid & 15;
    const int lq  = (tid >> 4) & 3;
    const int gbase = blockIdx.x * GPB;

    // ---- prefetch this block's offs slice (17 ints)
    if (tid < GPB + 1) offl[tid] = offs[gbase + tid];

    // ---- stage z: 16x256 fp32 -> bf16 LDS (1024 float4, 1/thread)
    {
        const float4* zsrc = (const float4*)(z + (size_t)gbase * LATENT);
        int row = tid >> 6, c4 = tid & 63;
        float4 v = zsrc[tid];
        short4 s4;
        s4.x = f2bf(v.x); s4.y = f2bf(v.y); s4.z = f2bf(v.z); s4.w = f2bf(v.w);
        *(short4*)&zs[row * ZS_S + c4 * 4] = s4;
    }
    __syncthreads();

    // ---- h = relu(z @ Wlp + b_lp), [16 x 512], K=256   (waves 0-7)
    if (w < 8) {
        const int cb = w * 64;
        f32x4 acc[4];
        #pragma unroll
        for (int ct = 0; ct < 4; ++ct) acc[ct] = (f32x4){0.f, 0.f, 0.f, 0.f};
        #pragma unroll
        for (int ks = 0; ks < LATENT / 32; ++ks) {
            bf16x8 a = *(const bf16x8*)&zs[l15 * ZS_S + ks * 32 + lq * 8];
            #pragma unroll
            for (int ct = 0; ct < 4; ++ct) {
                bf16x8 b = *(const bf16x8*)&wlp_t[(cb + ct * 16 + l15) * LATENT + ks * 32 + lq * 8];
                acc[ct] = __builtin_amdgcn_mfma_f32_16x16x32_bf16(a, b, acc[ct], 0, 0, 0);
            }
        }
        #pragma unroll
        for (int ct = 0; ct < 4; ++ct) {
            const int col = cb + ct * 16 + l15;
            const float bias = b_lp[col];
            #pragma unroll
            for (int i = 0; i < 4; ++i) {
                float v = acc[ct][i] + bias;
                hs[(lq * 4 + i) * HS_S + col] = f2bf(fmaxf(v, 0.f));
            }
        }
    }
    __syncthreads();

    // ---- hid = relu(h @ W1 + b1), [16 x 256], K=512   (waves 0-7)
    if (w < 8) {
        const int cb = w * 32;
        f32x4 acc[2];
        #pragma unroll
        for (int ct = 0; ct < 2; ++ct) acc[ct] = (f32x4){0.f, 0.f, 0.f, 0.f};
        #pragma unroll
        for (int ks = 0; ks < H2 / 32; ++ks) {
            bf16x8 a = *(const bf16x8*)&hs[l15 * HS_S + ks * 32 + lq * 8];
            #pragma unroll
            for (int ct = 0; ct < 2; ++ct) {
                bf16x8 b = *(const bf16x8*)&w1_t[(cb + ct * 16 + l15) * H2 + ks * 32 + lq * 8];
                acc[ct] = __builtin_amdgcn_mfma_f32_16x16x32_bf16(a, b, acc[ct], 0, 0, 0);
            }
        }
        #pragma unroll
        for (int ct = 0; ct < 2; ++ct) {
            const int col = cb + ct * 16 + l15;
            const float bias = b1[col];
            #pragma unroll
            for (int i = 0; i < 4; ++i) {
                float v = acc[ct][i] + bias;
                hd[(lq * 4 + i) * HD_S + col] = f2bf(fmaxf(v, 0.f));
            }
        }
    }
    __syncthreads();

    // ---- out_u = hid @ W2 + b2, [16 x 128], K=256   (waves 0-7)
    if (w < 8) {
        const int cb = w * 16;
        f32x4 acc = (f32x4){0.f, 0.f, 0.f, 0.f};
        #pragma unroll
        for (int ks = 0; ks < HID / 32; ++ks) {
            bf16x8 a = *(const bf16x8*)&hd[l15 * HD_S + ks * 32 + lq * 8];
            bf16x8 b = *(const bf16x8*)&w2_t[(cb + l15) * HID + ks * 32 + lq * 8];
            acc = __builtin_amdgcn_mfma_f32_16x16x32_bf16(a, b, acc, 0, 0, 0);
        }
        const int col = cb + l15;
        const float bias = b2[col];
        #pragma unroll
        for (int i = 0; i < 4; ++i)
            ous[(lq * 4 + i) * NF + col] = acc[i] + bias;
    }
    __syncthreads();

    // ---- scatter: wave w broadcasts graph gbase+w (16 waves, pure streams)
    {
        const int lane = tid & 63;
        const int lo = offl[w];
        const int hi = offl[w + 1];
        const f32x4 v = *(const f32x4*)&ous[w * NF + (lane & 31) * 4];

        f32x4* out4 = (f32x4*)out;
        for (int i = lo * (NF / 4) + lane; i < hi * (NF / 4); i += 64)
            out4[i] = v;
    }
}

// ---------------------------------------------------------------------------
extern "C" void kernel_launch(void* const* d_in, const int* in_sizes, int n_in,
                              void* d_out, int out_size, void* d_ws, size_t ws_size,
                              hipStream_t stream) {
    const float* z    = (const float*)d_in[0];
    const int*   seg  = (const int*)  d_in[1];
    const float* wlp  = (const float*)d_in[2];
    const float* b_lp = (const float*)d_in[3];
    const float* w1   = (const float*)d_in[4];
    const float* b1   = (const float*)d_in[5];
    const float* w2   = (const float*)d_in[6];
    const float* b2   = (const float*)d_in[7];
    float* out = (float*)d_out;

    short* wlp_t = (short*)d_ws;                 // [512][256] bf16
    short* w1_t  = wlp_t + LATENT * H2;          // [256][512] bf16
    short* w2_t  = w1_t + H2 * HID;              // [128][256] bf16
    int*   offs  = (int*)(w2_t + HID * NF);      // [4097]

    prep_kernel<<<PREP_BLOCKS + SCAN_BLOCKS, 256, 0, stream>>>(
        wlp, w1, w2, seg, wlp_t, w1_t, w2_t, offs);
    mlp_scatter_kernel<<<MBLOCKS, MTHREADS, 0, stream>>>(
        z, offs, wlp_t, w1_t, w2_t, b_lp, b1, b2, out);
}

// Round 16
// 48.093 us; speedup vs baseline: 3.1083x; 1.0260x over previous
//
#include <hip/hip_runtime.h>
#include <hip/hip_bf16.h>

typedef __attribute__((ext_vector_type(8))) short bf16x8;
typedef __attribute__((ext_vector_type(4))) float f32x4;

#define NGRAPH   4096
#define NNODES   262144
#define LATENT   256
#define H2       512
#define HID      256
#define NF       128

#define PREP_BLOCKS 1152       // weight transpose (294912 / 256)
#define SCAN_BLOCKS 64         // seg -> offs scan
#define IPT         16         // ints per scan thread (64*256*16 = 262144)

#define GPB      16            // graphs per block (merged kernel)
#define MTHREADS 512           // 8 waves
#define MBLOCKS  (NGRAPH / GPB)            // 256 -> 1 block/CU

// padded LDS strides
#define ZS_S 264
#define HS_S 520
#define HD_S 264

static __device__ __forceinline__ short f2bf(float x) {
    union { float f; unsigned u; } c; c.f = x;
    unsigned r = c.u + 0x7fffu + ((c.u >> 16) & 1u);   // RTNE
    return (short)(r >> 16);
}

// ---------------------------------------------------------------------------
// dispatch 1: weight transpose -> bf16 (blocks 0..1151) + seg scan -> offs
// (blocks 1152..1215).  offs[g] = first node index with seg >= g.
// ---------------------------------------------------------------------------
__global__ __launch_bounds__(256) void prep_kernel(
    const float* __restrict__ wlp, const float* __restrict__ w1,
    const float* __restrict__ w2, const int* __restrict__ seg,
    short* __restrict__ wlp_t, short* __restrict__ w1_t, short* __restrict__ w2_t,
    int* __restrict__ offs)
{
    const int b = blockIdx.x;
    if (b < PREP_BLOCKS) {
        int i = b * 256 + threadIdx.x;
        if (i < LATENT * H2) {                       // wlp_t [512][256]
            int n = i >> 8, k = i & 255;
            wlp_t[i] = f2bf(wlp[k * H2 + n]);
        } else if (i < 2 * LATENT * H2) {            // w1_t [256][512]
            int j = i - LATENT * H2;
            int n = j >> 9, k = j & 511;
            w1_t[j] = f2bf(w1[k * HID + n]);
        } else if (i < 2 * LATENT * H2 + HID * NF) { // w2_t [128][256]
            int j = i - 2 * LATENT * H2;
            int n = j >> 8, k = j & 255;
            w2_t[j] = f2bf(w2[k * NF + n]);
        }
    } else {
        const int st = (b - PREP_BLOCKS) * 256 + threadIdx.x;   // 0..16383
        const int base = st * IPT;
        int prev = (base == 0) ? -1 : seg[base - 1];
        int cur[IPT];
        #pragma unroll
        for (int j = 0; j < IPT; ++j) cur[j] = seg[base + j];
        #pragma unroll
        for (int j = 0; j < IPT; ++j) {
            int i = base + j;
            int s = cur[j];
            if (s != prev) {
                for (int g = prev + 1; g <= s; ++g) offs[g] = i;
            }
            prev = s;
        }
        if (base + IPT == NNODES) {                  // tail: (seg[N-1], NGRAPH]
            for (int g = prev + 1; g <= NGRAPH; ++g) offs[g] = NNODES;
        }
    }
}

// ---------------------------------------------------------------------------
// dispatch 2: 16-graph MLP (MFMA, full tiles) + per-wave streaming broadcast
// of the block's own 16 graphs via LDS (no global ou round-trip).
// 256 blocks = 1/CU; store phase covers every CU.
// ---------------------------------------------------------------------------
__global__ __launch_bounds__(MTHREADS) void mlp_scatter_kernel(
    const float* __restrict__ z, const int* __restrict__ offs,
    const short* __restrict__ wlp_t, const short* __restrict__ w1_t,
    const short* __restrict__ w2_t,
    const float* __restrict__ b_lp, const float* __restrict__ b1,
    const float* __restrict__ b2,
    float* __restrict__ out)
{
    __shared__ short zs[GPB * ZS_S];
    __shared__ short hs[GPB * HS_S];
    __shared__ short hd[GPB * HD_S];
    __shared__ float ous[GPB * NF];
    __shared__ int   offl[GPB + 1];

    const int tid = threadIdx.x;
    const int w   = tid >> 6;          // wave 0..7
    const int l15 = tid & 15;
    const int lq  = (tid >> 4) & 3;
    const int gbase = blockIdx.x * GPB;

    // ---- prefetch this block's offs slice (17 ints)
    if (tid < GPB + 1) offl[tid] = offs[gbase + tid];

    // ---- stage z: 16x256 fp32 -> bf16 LDS (padded)
    {
        const float4* zsrc = (const float4*)(z + (size_t)gbase * LATENT);
        #pragma unroll
        for (int it = 0; it < (GPB * LATENT / 4) / MTHREADS; ++it) {
            int idx = tid + it * MTHREADS;
            int row = idx >> 6, c4 = idx & 63;
            float4 v = zsrc[idx];
            short4 s4;
            s4.x = f2bf(v.x); s4.y = f2bf(v.y); s4.z = f2bf(v.z); s4.w = f2bf(v.w);
            *(short4*)&zs[row * ZS_S + c4 * 4] = s4;
        }
    }
    __syncthreads();

    // ---- h = relu(z @ Wlp + b_lp), [16 x 512], K=256
    {
        const int cb = w * 64;
        f32x4 acc[4];
        #pragma unroll
        for (int ct = 0; ct < 4; ++ct) acc[ct] = (f32x4){0.f, 0.f, 0.f, 0.f};
        #pragma unroll
        for (int ks = 0; ks < LATENT / 32; ++ks) {
            bf16x8 a = *(const bf16x8*)&zs[l15 * ZS_S + ks * 32 + lq * 8];
            #pragma unroll
            for (int ct = 0; ct < 4; ++ct) {
                bf16x8 b = *(const bf16x8*)&wlp_t[(cb + ct * 16 + l15) * LATENT + ks * 32 + lq * 8];
                acc[ct] = __builtin_amdgcn_mfma_f32_16x16x32_bf16(a, b, acc[ct], 0, 0, 0);
            }
        }
        #pragma unroll
        for (int ct = 0; ct < 4; ++ct) {
            const int col = cb + ct * 16 + l15;
            const float bias = b_lp[col];
            #pragma unroll
            for (int i = 0; i < 4; ++i) {
                float v = acc[ct][i] + bias;
                hs[(lq * 4 + i) * HS_S + col] = f2bf(fmaxf(v, 0.f));
            }
        }
    }
    __syncthreads();

    // ---- hid = relu(h @ W1 + b1), [16 x 256], K=512
    {
        const int cb = w * 32;
        f32x4 acc[2];
        #pragma unroll
        for (int ct = 0; ct < 2; ++ct) acc[ct] = (f32x4){0.f, 0.f, 0.f, 0.f};
        #pragma unroll
        for (int ks = 0; ks < H2 / 32; ++ks) {
            bf16x8 a = *(const bf16x8*)&hs[l15 * HS_S + ks * 32 + lq * 8];
            #pragma unroll
            for (int ct = 0; ct < 2; ++ct) {
                bf16x8 b = *(const bf16x8*)&w1_t[(cb + ct * 16 + l15) * H2 + ks * 32 + lq * 8];
                acc[ct] = __builtin_amdgcn_mfma_f32_16x16x32_bf16(a, b, acc[ct], 0, 0, 0);
            }
        }
        #pragma unroll
        for (int ct = 0; ct < 2; ++ct) {
            const int col = cb + ct * 16 + l15;
            const float bias = b1[col];
            #pragma unroll
            for (int i = 0; i < 4; ++i) {
                float v = acc[ct][i] + bias;
                hd[(lq * 4 + i) * HD_S + col] = f2bf(fmaxf(v, 0.f));
            }
        }
    }
    __syncthreads();

    // ---- out_u = hid @ W2 + b2, [16 x 128], K=256
    {
        const int cb = w * 16;
        f32x4 acc = (f32x4){0.f, 0.f, 0.f, 0.f};
        #pragma unroll
        for (int ks = 0; ks < HID / 32; ++ks) {
            bf16x8 a = *(const bf16x8*)&hd[l15 * HD_S + ks * 32 + lq * 8];
            bf16x8 b = *(const bf16x8*)&w2_t[(cb + l15) * HID + ks * 32 + lq * 8];
            acc = __builtin_amdgcn_mfma_f32_16x16x32_bf16(a, b, acc, 0, 0, 0);
        }
        const int col = cb + l15;
        const float bias = b2[col];
        #pragma unroll
        for (int i = 0; i < 4; ++i)
            ous[(lq * 4 + i) * NF + col] = acc[i] + bias;
    }
    __syncthreads();

    // ---- scatter: wave w broadcasts graphs gbase+2w, gbase+2w+1 (pure
    //      store streams; rows read once from LDS)
    {
        const int lane = tid & 63;
        f32x4* out4 = (f32x4*)out;
        #pragma unroll
        for (int q = 0; q < 2; ++q) {
            const int r = w * 2 + q;               // local row 0..15
            const int lo = offl[r];
            const int hi = offl[r + 1];
            const f32x4 v = *(const f32x4*)&ous[r * NF + (lane & 31) * 4];
            for (int i = lo * (NF / 4) + lane; i < hi * (NF / 4); i += 64)
                out4[i] = v;
        }
    }
}

// ---------------------------------------------------------------------------
extern "C" void kernel_launch(void* const* d_in, const int* in_sizes, int n_in,
                              void* d_out, int out_size, void* d_ws, size_t ws_size,
                              hipStream_t stream) {
    const float* z    = (const float*)d_in[0];
    const int*   seg  = (const int*)  d_in[1];
    const float* wlp  = (const float*)d_in[2];
    const float* b_lp = (const float*)d_in[3];
    const float* w1   = (const float*)d_in[4];
    const float* b1   = (const float*)d_in[5];
    const float* w2   = (const float*)d_in[6];
    const float* b2   = (const float*)d_in[7];
    float* out = (float*)d_out;

    short* wlp_t = (short*)d_ws;                 // [512][256] bf16
    short* w1_t  = wlp_t + LATENT * H2;          // [256][512] bf16
    short* w2_t  = w1_t + H2 * HID;              // [128][256] bf16
    int*   offs  = (int*)(w2_t + HID * NF);      // [4097]

    prep_kernel<<<PREP_BLOCKS + SCAN_BLOCKS, 256, 0, stream>>>(
        wlp, w1, w2, seg, wlp_t, w1_t, w2_t, offs);
    mlp_scatter_kernel<<<MBLOCKS, MTHREADS, 0, stream>>>(
        z, offs, wlp_t, w1_t, w2_t, b_lp, b1, b2, out);
}